// Round 4
// baseline (3378.158 us; speedup 1.0000x reference)
//
#include <hip/hip_runtime.h>

// SCRN 2-layer + fc head — PERSISTENT PIPELINE, round 4: e-stage FUSED INTO scan2.
// Round-3 post-mortem: ring shrink was near-neutral (1704->1627); FETCH stayed ~=consumed
// published data because agent-scope polls bypass L2 structurally (LLC=256MB held both ring
// sizes). Real cost: the e-stage added a full publish->discover hop to the chain and scan1's
// own peer exchange ran through the ring instead of the proven hot 2-slot (2.55 us/step).
// This round removes the e-hop entirely:
//   scan1 (8 blocks, 2-way): PROVEN standalone loop (hot 2-slot hb1 peer exchange) +
//          fire-and-forget duplicate publish of h1_t into a 32-slot ring for scan2;
//          gated on cached scan2 progress (~1 LLC load / ~28 steps).
//   scan2 (16 blocks = 4 groups x 4 col-quarters, fused e): ingests full h1_t slab from the
//          ring (prefetched 1 step ahead -> first poll hits), computes e_t = h1_t@W2^T and
//          keeps the d2-EMA in f32 REGISTERS (d2 never touches memory), then
//          h2_t = tanh(d2_t + h2_{t-1}@Vh1^T) with a 4-way hb2 peer exchange (one RT/step).
// Per-step critical path per stage: 32 MFMA + ONE LLC round trip. d2r ring + e-blocks gone.

typedef _Float16 f16;
typedef _Float16 f16x8 __attribute__((ext_vector_type(8)));
typedef _Float16 f16x2 __attribute__((ext_vector_type(2)));
typedef float f32x4 __attribute__((ext_vector_type(4)));
typedef unsigned short u16;
typedef unsigned int u32;
typedef unsigned short u16x8 __attribute__((ext_vector_type(8)));
typedef unsigned long long u64;

#define DEV __device__ __forceinline__

constexpr int Tt = 512, HIDq = 512;
constexpr int RS = 32;   // h1 ring slots (4 MiB)

DEV float bf2f(u16 u) { unsigned v = ((unsigned)u) << 16; float f; __builtin_memcpy(&f, &v, 4); return f; }
DEV u16 f2bf(float f) { unsigned u; __builtin_memcpy(&u, &f, 4); u = (u + 0x7fffu + ((u >> 16) & 1u)) >> 16; return (u16)u; }
DEV float fast_tanh(float x) {
  x = fminf(30.f, fmaxf(-30.f, x));
  float e = exp2f(x * 2.885390081777927f);   // e^(2x)
  return (e - 1.f) / (e + 1.f);
}
DEV u64 al64(const u64* p) { return __hip_atomic_load(p, __ATOMIC_RELAXED, __HIP_MEMORY_SCOPE_AGENT); }
DEV u32 al32(const u32* p) { return __hip_atomic_load(p, __ATOMIC_RELAXED, __HIP_MEMORY_SCOPE_AGENT); }
DEV void as32(u32* p, u32 v) { __hip_atomic_store(p, v, __ATOMIC_RELAXED, __HIP_MEMORY_SCOPE_AGENT); }

// ---- dtype probe: Wx0 entries bounded by 1/16; bf16 decode of f32 mantissa halves -> huge ----
__global__ void k_probe(const u16* __restrict__ w, int* __restrict__ dmode) {
  __shared__ int s;
  if (threadIdx.x == 0) s = 0;
  __syncthreads();
  int found = 0;
  for (int i = threadIdx.x; i < 8192; i += 256) {
    float v = bf2f(w[i]);
    if (fabsf(v) > 0.5f) found = 1;
  }
  if (found) atomicOr(&s, 1);
  __syncthreads();
  if (threadIdx.x == 0) *dmode = s;   // 0 = bf16 buffers, 1 = f32 buffers
}

// ---- convert n8*8 elements (bf16 or f32 per mode) -> fp16 ----
__global__ void k_cvt(const void* __restrict__ src, f16* __restrict__ dst, int n8,
                      const int* __restrict__ dmode) {
  int i = blockIdx.x * 256 + threadIdx.x;
  if (i >= n8) return;
  f16x8 o;
  if (*dmode) {
    const float4* s = (const float4*)src;
    float4 a = s[2*i], b = s[2*i+1];
    o[0]=(f16)a.x; o[1]=(f16)a.y; o[2]=(f16)a.z; o[3]=(f16)a.w;
    o[4]=(f16)b.x; o[5]=(f16)b.y; o[6]=(f16)b.z; o[7]=(f16)b.w;
  } else {
    u16x8 v = ((const u16x8*)src)[i];
#pragma unroll
    for (int j = 0; j < 8; ++j) o[j] = (f16)bf2f(v[j]);
  }
  ((f16x8*)dst)[i] = o;
}

__global__ void k_zero(u16* __restrict__ out) {  // diagnostic fallback (ws too small)
  out[blockIdx.x * 256 + threadIdx.x] = 0;
}

// ---- transpose [R][2^cshift] -> [2^cshift][R] (small weights only) ----
__global__ __launch_bounds__(256) void k_tr(const f16* __restrict__ src, f16* __restrict__ dst,
                                            int R, int cshift) {
  int idx = blockIdx.x * 256 + threadIdx.x;
  int r = idx >> cshift, c = idx & ((1 << cshift) - 1);
  dst[c * R + r] = src[idx];
}

// ---- b2[j] = sum_c Uc1[j,c] * bx1[c] ----
__global__ __launch_bounds__(512) void k_bias(const f16* __restrict__ Uc, const f16* __restrict__ bx,
                                              f16* __restrict__ out) {
  int j = threadIdx.x;
  float a = 0.f;
  for (int c = 0; c < 256; ++c) a += (float)Uc[j * 256 + c] * (float)bx[c];
  out[j] = (f16)a;
}

// ---- EMA c_t = 0.05 c_{t-1} + 0.95 xp_t ; 16-step warmup per 64-chunk (batch-major) ----
__global__ __launch_bounds__(128) void k_ema(const f16* __restrict__ xp, f16* __restrict__ c) {
  int b = blockIdx.x >> 3, chunk = blockIdx.x & 7;
  int t0 = chunk * 64;
  int ch = threadIdx.x;
  const f16x2* src = (const f16x2*)(xp + (size_t)b * Tt * 256) + ch;
  f16x2* dst = (f16x2*)(c + (size_t)b * Tt * 256) + ch;
  float c0 = 0.f, c1 = 0.f;
  int ts = (t0 >= 16) ? t0 - 16 : 0;
  for (int tt = ts; tt < t0 + 64; ++tt) {
    f16x2 v = src[(size_t)tt * 128];
    c0 = 0.05f * c0 + 0.95f * (float)v.x;
    c1 = 0.05f * c1 + 0.95f * (float)v.y;
    if (tt >= t0) { f16x2 o; o.x = (f16)c0; o.y = (f16)c1; dst[(size_t)tt * 128] = o; }
  }
}

// ---- GEMM: C = A[M,K] @ B[N,K]^T (+bias). TD: store C time-major (row b*512+t -> t*64+b) ----
template<bool HAS_BIAS, bool TD>
__global__ __launch_bounds__(256) void k_gemm(const f16* __restrict__ A, const f16* __restrict__ Bm,
                                              const f16* __restrict__ bias, f16* __restrict__ C,
                                              int M, int N, int K) {
  __shared__ f16 As[128][40];
  __shared__ f16 Bs[128][40];
  const int tid = threadIdx.x, lane = tid & 63, wv = tid >> 6;
  const int l15 = lane & 15, q = lane >> 4;
  const int wm = wv >> 1, wn = wv & 1;
  const int m0 = blockIdx.y * 128, n0 = blockIdx.x * 128;
  const int srow = tid >> 1, sseg = tid & 1;
  f32x4 acc[4][4] = {};
  const f16* ga = A  + (size_t)(m0 + srow) * K + sseg * 16;
  const f16* gb = Bm + (size_t)(n0 + srow) * K + sseg * 16;
  for (int k0 = 0; k0 < K; k0 += 32) {
    f16x8 a0 = *(const f16x8*)(ga + k0);
    f16x8 a1 = *(const f16x8*)(ga + k0 + 8);
    f16x8 b0 = *(const f16x8*)(gb + k0);
    f16x8 b1 = *(const f16x8*)(gb + k0 + 8);
    __syncthreads();
    *(f16x8*)&As[srow][sseg*16]     = a0;
    *(f16x8*)&As[srow][sseg*16 + 8] = a1;
    *(f16x8*)&Bs[srow][sseg*16]     = b0;
    *(f16x8*)&Bs[srow][sseg*16 + 8] = b1;
    __syncthreads();
    f16x8 af[4], bf[4];
#pragma unroll
    for (int i = 0; i < 4; ++i) af[i] = *(const f16x8*)&As[wm*64 + i*16 + l15][q*8];
#pragma unroll
    for (int i = 0; i < 4; ++i) bf[i] = *(const f16x8*)&Bs[wn*64 + i*16 + l15][q*8];
#pragma unroll
    for (int i = 0; i < 4; ++i)
#pragma unroll
      for (int j = 0; j < 4; ++j)
        acc[i][j] = __builtin_amdgcn_mfma_f32_16x16x32_f16(af[i], bf[j], acc[i][j], 0, 0, 0);
  }
#pragma unroll
  for (int j = 0; j < 4; ++j) {
    int col = n0 + wn*64 + j*16 + l15;
    float bv = HAS_BIAS ? (float)bias[col] : 0.f;
#pragma unroll
    for (int i = 0; i < 4; ++i)
#pragma unroll
      for (int r = 0; r < 4; ++r) {
        int row = m0 + wm*64 + i*16 + q*4 + r;
        size_t orow = TD ? (size_t)((row & 511) * 64 + (row >> 9)) : (size_t)row;
        C[orow * N + col] = (f16)(acc[i][j][r] + bv);
      }
  }
}

// ---- persistent mega-kernel: scan1 (blocks 0-7) | fused scan2+e (blocks 8-23) ----
// hb1 : h1 tagged, 2 slots [2][64][512] u32 — scan1's PROVEN hot peer exchange
// ring: h1 tagged, 32 slots x [64][512] u32 (slot=t&31, tag=t+1) — duplicate publish for scan2
// hb2 : h2 tagged, 2 slots — scan2's 4-way peer exchange (+ head reads slot 1)
// prog: 16 u32, scan2 block (g,qr) writes t at top of step t (h1_t ingested) -> gates scan1
__global__ __launch_bounds__(512, 2) void k_mega(const f16* __restrict__ Vh0,
                                                 const f16* __restrict__ Vh1,
                                                 const f16* __restrict__ W2,
                                                 const f16* __restrict__ b2,
                                                 const f16* __restrict__ d1,
                                                 u32* __restrict__ ring,
                                                 u32* __restrict__ hb1,
                                                 u32* __restrict__ hb2,
                                                 u32* __restrict__ prog) {
  __shared__ f16 hL[2][16][520];   // scan1: h1 state | scan2: h2 state
  __shared__ f16 hM[2][16][520];   // scan2 only: ingested h1 tile (double-buffered)
  const int bb = blockIdx.x;
  const int tid = threadIdx.x, w = tid >> 6, lane = tid & 63;
  const int l15 = lane & 15, q = lane >> 4;

  if (bb < 8) {
    // ============ scan1: h1_t = tanh(d1_t + h1_{t-1} @ Vh0^T) -> hb1 (+ ring) ============
    const int hf = bb & 1, g = bb >> 1;
    const int colbase = 256*hf + 32*w;
    f16x8 Bf[2][16];
#pragma unroll
    for (int j = 0; j < 2; ++j)
#pragma unroll
      for (int kk = 0; kk < 16; ++kk)
        Bf[j][kk] = *(const f16x8*)&Vh0[(size_t)(colbase + 16*j + l15) * HIDq + kk*32 + q*8];
    for (int i = tid; i < 1024; i += 512) {
      int r = i >> 6, c = (i & 63) * 8;
      f16x8 z = {};
      *(f16x8*)&hL[0][r][c] = z;
    }
    float dv[2][4];
#pragma unroll
    for (int j = 0; j < 2; ++j)
#pragma unroll
      for (int r = 0; r < 4; ++r)
        dv[j][r] = (float)d1[(size_t)(16*g + q*4 + r) * HIDq + colbase + 16*j + l15];
    __syncthreads();
    const int irow = tid >> 5, ic8 = (tid & 31) * 8;
    const int pcol = 256*(hf ^ 1) + ic8;
    int prog_c = 0;   // cached min(scan2 progress) for our group

    for (int t = 0; t < Tt; ++t) {
      const int rb = t & 1, wb = rb ^ 1, slot = t & 1;
      f32x4 a00 = {}, a01 = {}, a10 = {}, a11 = {};
#pragma unroll
      for (int kk = 0; kk < 16; ++kk) {
        f16x8 a = *(const f16x8*)&hL[rb][l15][kk*32 + q*8];
        if (kk & 1) {
          a01 = __builtin_amdgcn_mfma_f32_16x16x32_f16(a, Bf[0][kk], a01, 0, 0, 0);
          a11 = __builtin_amdgcn_mfma_f32_16x16x32_f16(a, Bf[1][kk], a11, 0, 0, 0);
        } else {
          a00 = __builtin_amdgcn_mfma_f32_16x16x32_f16(a, Bf[0][kk], a00, 0, 0, 0);
          a10 = __builtin_amdgcn_mfma_f32_16x16x32_f16(a, Bf[1][kk], a10, 0, 0, 0);
        }
      }
      const u32 tagw = (u32)(t + 1) << 16;
      u32* rslot = ring + (size_t)(t & (RS - 1)) * 32768;
      u16 hbits[2][4];
#pragma unroll
      for (int j = 0; j < 2; ++j) {
        f32x4 s = j ? (a10 + a11) : (a00 + a01);
#pragma unroll
        for (int r = 0; r < 4; ++r) {
          float z = s[r] + dv[j][r];
          union { f16 h; u16 u; } cv; cv.h = (f16)fast_tanh(z);
          hbits[j][r] = cv.u;
          size_t off = (size_t)(16*g + q*4 + r) * HIDq + colbase + 16*j + l15;
          as32(&hb1[(size_t)slot * 32768 + off], tagw | (u32)cv.u);   // hot peer exchange
          as32(&rslot[off], tagw | (u32)cv.u);                        // scan2 feed (fire&forget)
        }
      }
#pragma unroll
      for (int j = 0; j < 2; ++j)
#pragma unroll
        for (int r = 0; r < 4; ++r) {
          union { u16 u; f16 h; } cv; cv.u = hbits[j][r];
          hL[wb][q*4 + r][colbase + 16*j + l15] = cv.h;
        }
      if (t < Tt - 1) {
#pragma unroll
        for (int j = 0; j < 2; ++j)
#pragma unroll
          for (int r = 0; r < 4; ++r)
            dv[j][r] = (float)d1[((size_t)(t+1)*64 + 16*g + q*4 + r) * HIDq + colbase + 16*j + l15];
      }
      // ring gate for NEXT step's publish (slot (t+1)&31 holds h1_{t-31}; all 4 scan2
      // blocks of group g must have ingested it: min(prog[4g..4g+3]) >= t-31). Cached;
      // ordered before next publish by the loop-end barrier. Overlaps peer-ingest RT.
      if (tid == 0 && prog_c < t - 31) {
        const u64* pq = (const u64*)&prog[4 * g];
        for (;;) {
          u64 p0 = al64(pq), p1 = al64(pq + 1);
          int a = (int)(u32)p0, b = (int)(u32)(p0 >> 32);
          int c = (int)(u32)p1, d = (int)(u32)(p1 >> 32);
          int m = a < b ? a : b, n = c < d ? c : d;
          prog_c = m < n ? m : n;
          if (prog_c >= t - 31) break;
          __builtin_amdgcn_s_sleep(1);
        }
      }
      // peer slab ingest from hb1 (proven hot 2-slot exchange)
      {
        const u64* pp = (const u64*)(hb1 + (size_t)slot * 32768 + (size_t)(16*g + irow) * HIDq)
                      + (pcol >> 1);
        u64 v[4];
#pragma unroll
        for (int jj = 0; jj < 4; ++jj) v[jj] = al64(pp + jj);
        for (;;) {
          u32 bad = 0;
#pragma unroll
          for (int jj = 0; jj < 4; ++jj)
            bad |= ((u32)v[jj] ^ tagw) | ((u32)(v[jj] >> 32) ^ tagw);
          if ((bad & 0xFFFF0000u) == 0) break;
          __builtin_amdgcn_s_sleep(1);
#pragma unroll
          for (int jj = 0; jj < 4; ++jj) v[jj] = al64(pp + jj);
        }
        union { u32 wd[4]; f16x8 vv; } fr;
#pragma unroll
        for (int jj = 0; jj < 4; ++jj)
          fr.wd[jj] = __builtin_amdgcn_perm((u32)(v[jj] >> 32), (u32)v[jj], 0x05040100u);
        *(f16x8*)&hL[wb][irow][pcol] = fr.vv;
      }
      __syncthreads();
    }

  } else {
    // ==== scan2+e fused: h2_t = tanh( EMA(h1_t@W2^T + b2) + h2_{t-1}@Vh1^T ) -> hb2 ====
    // 16 blocks = 4 groups x 4 col-quarters; per wave 16 out cols; d2-EMA in f32 regs.
    const int sb = bb - 8, g = sb >> 2, qr = sb & 3;
    const int colbase = 128*qr + 16*w;
    f16x8 BfV[16], BfE[16];
#pragma unroll
    for (int kk = 0; kk < 16; ++kk) {
      BfV[kk] = *(const f16x8*)&Vh1[(size_t)(colbase + l15) * HIDq + kk*32 + q*8];
      BfE[kk] = *(const f16x8*)&W2 [(size_t)(colbase + l15) * HIDq + kk*32 + q*8];
    }
    float bve = (float)b2[colbase + l15];
    float ed[4] = {};
    for (int i = tid; i < 1024; i += 512) {
      int r = i >> 6, c = (i & 63) * 8;
      f16x8 z = {};
      *(f16x8*)&hL[0][r][c] = z;
    }
    const int irow = tid >> 5, t32 = tid & 31;
    // peer-ingest col map: 3 quarters (384 cols), per-u64 (2-col) mapping skips own quarter
    int acs[6];
#pragma unroll
    for (int j = 0; j < 6; ++j) {
      int c0 = t32 * 12 + 2 * j;
      acs[j] = c0 + (c0 >= 128 * qr ? 128 : 0);
    }
    const int hc0 = t32 * 16;   // h1-ingest cols: 16 per thread (8 u64)
    // prologue: ingest h1_0 (ring slot 0, tag 1) -> hM[0]
    {
      const u64* hrow = (const u64*)(ring + (size_t)(16*g + irow) * HIDq) + (hc0 >> 1);
      u64 vh[8];
#pragma unroll
      for (int j = 0; j < 8; ++j) vh[j] = al64(hrow + j);
      const u32 tagH = 1u << 16;
      for (;;) {
        u32 bad = 0;
#pragma unroll
        for (int j = 0; j < 8; ++j)
          bad |= ((u32)vh[j] ^ tagH) | ((u32)(vh[j] >> 32) ^ tagH);
        if ((bad & 0xFFFF0000u) == 0) break;
        __builtin_amdgcn_s_sleep(1);
#pragma unroll
        for (int j = 0; j < 8; ++j) vh[j] = al64(hrow + j);
      }
#pragma unroll
      for (int j = 0; j < 8; ++j)
        *(u32*)&hM[0][irow][hc0 + 2*j] =
            __builtin_amdgcn_perm((u32)(vh[j] >> 32), (u32)vh[j], 0x05040100u);
    }
    __syncthreads();

    for (int t = 0; t < Tt; ++t) {
      const int rb = t & 1, wb = rb ^ 1, slot = t & 1;
      if (tid == 0 && t > 0) as32(&prog[sb], (u32)t);   // h1_t ingested (end of step t-1)
      // MFMA: Vh1 tile (A = h2_{t-1} in hL[rb]) + W2 tile (A = h1_t in hM[rb]); 4 chains
      f32x4 v0 = {}, v1 = {}, e0 = {}, e1 = {};
#pragma unroll
      for (int kk = 0; kk < 16; ++kk) {
        f16x8 a2 = *(const f16x8*)&hL[rb][l15][kk*32 + q*8];
        f16x8 a1 = *(const f16x8*)&hM[rb][l15][kk*32 + q*8];
        if (kk & 1) {
          v1 = __builtin_amdgcn_mfma_f32_16x16x32_f16(a2, BfV[kk], v1, 0, 0, 0);
          e1 = __builtin_amdgcn_mfma_f32_16x16x32_f16(a1, BfE[kk], e1, 0, 0, 0);
        } else {
          v0 = __builtin_amdgcn_mfma_f32_16x16x32_f16(a2, BfV[kk], v0, 0, 0, 0);
          e0 = __builtin_amdgcn_mfma_f32_16x16x32_f16(a1, BfE[kk], e0, 0, 0, 0);
        }
      }
      const u32 tagw = (u32)(t + 1) << 16;
      f32x4 sv = v0 + v1, se = e0 + e1;
      u16 hbits[4];
#pragma unroll
      for (int r = 0; r < 4; ++r) {
        ed[r] = 0.05f * ed[r] + 0.95f * (se[r] + bve);   // d2_t, f32-resident
        float z = sv[r] + ed[r];
        union { f16 h; u16 u; } cv; cv.h = (f16)fast_tanh(z);
        hbits[r] = cv.u;
        as32(&hb2[(size_t)(slot*64 + 16*g + q*4 + r) * HIDq + colbase + l15],
             tagw | (u32)cv.u);
      }
#pragma unroll
      for (int r = 0; r < 4; ++r) {
        union { u16 u; f16 h; } cv; cv.u = hbits[r];
        hL[wb][q*4 + r][colbase + l15] = cv.h;
      }
      // combined wait: 3 peer h2 slabs (6 u64, tag t+1) + h1_{t+1} prefetch (8 u64, tag t+2)
      {
        const bool hh = (t < Tt - 1);
        const u32 tagH = (u32)(t + 2) << 16;
        const u64* prow = (const u64*)(hb2 + (size_t)(slot*64 + 16*g + irow) * HIDq);
        const u64* hrow = (const u64*)(ring + (size_t)((t+1) & (RS-1)) * 32768
                            + (size_t)(16*g + irow) * HIDq) + (hc0 >> 1);
        u64 vp[6], vh[8];
#pragma unroll
        for (int j = 0; j < 6; ++j) vp[j] = al64(prow + (acs[j] >> 1));
        if (hh) {
#pragma unroll
          for (int j = 0; j < 8; ++j) vh[j] = al64(hrow + j);
        }
        for (;;) {
          u32 badp = 0;
#pragma unroll
          for (int j = 0; j < 6; ++j)
            badp |= ((u32)vp[j] ^ tagw) | ((u32)(vp[j] >> 32) ^ tagw);
          badp &= 0xFFFF0000u;
          u32 badh = 0;
          if (hh) {
#pragma unroll
            for (int j = 0; j < 8; ++j)
              badh |= ((u32)vh[j] ^ tagH) | ((u32)(vh[j] >> 32) ^ tagH);
            badh &= 0xFFFF0000u;
          }
          if (!(badp | badh)) break;
          __builtin_amdgcn_s_sleep(1);
          if (badp) {
#pragma unroll
            for (int j = 0; j < 6; ++j) vp[j] = al64(prow + (acs[j] >> 1));
          }
          if (badh) {
#pragma unroll
            for (int j = 0; j < 8; ++j) vh[j] = al64(hrow + j);
          }
        }
#pragma unroll
        for (int j = 0; j < 6; ++j)
          *(u32*)&hL[wb][irow][acs[j]] =
              __builtin_amdgcn_perm((u32)(vp[j] >> 32), (u32)vp[j], 0x05040100u);
        if (hh) {
#pragma unroll
          for (int j = 0; j < 8; ++j)
            *(u32*)&hM[wb][irow][hc0 + 2*j] =
                __builtin_amdgcn_perm((u32)(vh[j] >> 32), (u32)vh[j], 0x05040100u);
        }
      }
      __syncthreads();   // hL[wb] (h2_t) + hM[wb] (h1_{t+1}) complete for step t+1
    }
  }
}

// ---- final: out[64,128] = h_last[64,512] @ fc_w^T + fc_b; h from tagged buffer ----
__global__ __launch_bounds__(64) void k_final(const u32* __restrict__ h, const f16* __restrict__ fw,
                                              const f16* __restrict__ fb, void* __restrict__ outv,
                                              const int* __restrict__ dmode) {
  __shared__ f16 hA[16][520];
  __shared__ f16 Bw[16][520];
  const int mb = blockIdx.x & 3, nb = blockIdx.x >> 2;
  const int lane = threadIdx.x, l15 = lane & 15, q = lane >> 4;
  for (int i = lane; i < 16 * 128; i += 64) {   // tagged u32 -> f16 (low 16)
    int r = i >> 7, c = (i & 127) * 4;
    const u64* p = (const u64*)&h[(size_t)(mb*16 + r) * 512 + c];
    u64 v0 = al64(p), v1 = al64(p + 1);
    *(u32*)&hA[r][c]     = __builtin_amdgcn_perm((u32)(v0 >> 32), (u32)v0, 0x05040100u);
    *(u32*)&hA[r][c + 2] = __builtin_amdgcn_perm((u32)(v1 >> 32), (u32)v1, 0x05040100u);
  }
  for (int i = lane; i < 16 * 64; i += 64) {
    int r = i >> 6, c = (i & 63) * 8;
    *(f16x8*)&Bw[r][c] = *(const f16x8*)&fw[(size_t)(nb*16 + r) * 512 + c];
  }
  __syncthreads();
  f32x4 acc = {};
#pragma unroll
  for (int kk = 0; kk < 16; ++kk) {
    f16x8 a = *(const f16x8*)&hA[l15][kk*32 + q*8];
    f16x8 b = *(const f16x8*)&Bw[l15][kk*32 + q*8];
    acc = __builtin_amdgcn_mfma_f32_16x16x32_f16(a, b, acc, 0, 0, 0);
  }
  float bv = (float)fb[nb*16 + l15];
  int md = *dmode;
#pragma unroll
  for (int r = 0; r < 4; ++r) {
    int idx = (mb*16 + q*4 + r) * 128 + nb*16 + l15;
    float val = acc[r] + bv;
    if (md) ((float*)outv)[idx] = val;
    else    ((u16*)outv)[idx]   = f2bf(val);
  }
}

extern "C" void kernel_launch(void* const* d_in, const int* in_sizes, int n_in,
                              void* d_out, int out_size, void* d_ws, size_t ws_size,
                              hipStream_t stream) {
  if (ws_size < 88080384ull) {
    k_zero<<<32, 256, 0, stream>>>((u16*)d_out);
    return;
  }
  char* ws = (char*)d_ws;
  // ---- control / tagged buffers ----
  u32* hb2   = (u32*)(ws + 0);           // h2 tagged, 2 slots: 256 KiB
  u32* hb1   = (u32*)(ws + 262144);      // h1 tagged, 2 slots: 256 KiB (hot peer exchange)
  u32* prog  = (u32*)(ws + 524288);      // 16 u32 scan2 progress
  int* dmode = (int*)(ws + 524352);
  // ---- weights (f16) ----
  f16* Wx0f = (f16*)(ws + 1048576);      // 131072 B
  f16* Uc0f = (f16*)(ws + 1179648);      // 262144
  f16* Vh0f = (f16*)(ws + 1441792);      // 524288
  f16* Wx1f = (f16*)(ws + 1966080);      // 262144
  f16* Uc1f = (f16*)(ws + 2228224);      // 262144
  f16* Vh1f = (f16*)(ws + 2490368);      // 524288
  f16* fcwf = (f16*)(ws + 3014656);      // 131072
  f16* bx0f = (f16*)(ws + 3145728);      // 512
  f16* bx1f = (f16*)(ws + 3146240);      // 512
  f16* fcbf = (f16*)(ws + 3146752);      // 256
  f16* Wx1T = (f16*)(ws + 3147776);      // 262144  (Wx1 transposed [512][256])
  f16* W2f  = (f16*)(ws + 3409920);      // 524288  (Uc1 @ Wx1, [512][512])
  f16* b2f  = (f16*)(ws + 3934208);      // 1024    (Uc1 @ bx1)
  // ---- big buffers (with lifetime overlays) ----
  f16* x16  = (f16*)(ws + 4194304);      // 16 MiB, dead after xp1-gemm
  u32* ring = (u32*)(ws + 4194304);      // 4 MiB: h1 ring (32 slots), overlays x16
  f16* xp1  = (f16*)(ws + 20971520);     // 16 MiB, dead after ema
  f16* cb1  = (f16*)(ws + 37748736);     // 16 MiB, dead after d1-gemm
  f16* d1   = (f16*)(ws + 54525952);     // 32 MiB, time-major [t][64][512], persists

  hipMemsetAsync(ws, 0, 524352, stream);                        // hb2 + hb1 + prog
  k_probe<<<1, 256, 0, stream>>>((const u16*)d_in[1], dmode);
  auto cvt = [&](const void* s, f16* d, int n) {
    int n8 = n / 8;
    k_cvt<<<dim3((n8 + 255) / 256), dim3(256), 0, stream>>>(s, d, n8, dmode);
  };
  cvt(d_in[0],  x16,  8388608);
  cvt(d_in[1],  Wx0f, 65536);
  cvt(d_in[2],  bx0f, 256);
  cvt(d_in[3],  Uc0f, 131072);
  cvt(d_in[4],  Vh0f, 262144);
  cvt(d_in[5],  Wx1f, 131072);
  cvt(d_in[6],  bx1f, 256);
  cvt(d_in[7],  Uc1f, 131072);
  cvt(d_in[8],  Vh1f, 262144);
  cvt(d_in[9],  fcwf, 65536);
  cvt(d_in[10], fcbf, 128);

  // layer-2 weight merge: W2 = Uc1 @ Wx1, b2 = Uc1 @ bx1
  k_tr<<<512, 256, 0, stream>>>(Wx1f, Wx1T, 256, 9);
  k_bias<<<1, 512, 0, stream>>>(Uc1f, bx1f, b2f);
  k_gemm<false, false><<<dim3(4, 4), 256, 0, stream>>>(Uc1f, Wx1T, nullptr, W2f, 512, 512, 256);

  // layer-1 front (unchanged proven path): xp1 -> EMA -> d1 (time-major)
  k_gemm<true , false><<<dim3(2, 256), 256, 0, stream>>>(x16, Wx0f, bx0f, xp1, 32768, 256, 256);
  k_ema<<<512, 128, 0, stream>>>(xp1, cb1);
  hipMemsetAsync(ws + 4194304, 0, 4194304, stream);             // h1 ring (x16 now dead)
  k_gemm<false, true ><<<dim3(4, 256), 256, 0, stream>>>(cb1, Uc0f, nullptr, d1, 32768, 512, 256);

  // fused pipeline: scan1 || scan2+e
  k_mega<<<24, 512, 0, stream>>>(Vh0f, Vh1f, W2f, b2f, d1, ring, hb1, hb2, prog);

  // head: h2_511 (slot 1) in hb2 (tagged)
  k_final<<<32, 64, 0, stream>>>(hb2 + 64 * 512, fcwf, fcbf, d_out, dmode);
}